// Round 4
// baseline (226.037 us; speedup 1.0000x reference)
//
#include <hip/hip_runtime.h>
#include <math.h>

// Problem: FVMemoryBank
//   inputs (f32 unless noted):
//     d_in[0] audio_emb  [bs=4096, dim=128]
//     d_in[1] video_emb  [4096, 128]
//     d_in[2] view1_mem  [mem=500000, 128]
//     d_in[3] view2_mem  [500000, 128]
//     d_in[4] y          [4096] int32
//   output: concat(new_view1, new_view2) flat f32 — 2 x 500000 x 128
//
// new_viewK = viewK_mem, except rows y[i] replaced by
//   l2norm( viewK_mem[y[i]]*0.5 + l2norm(embK[i])*0.5 )
//
// Strategy: one grid-stride streaming copy kernel, 4x dwordx4 per thread per
// iteration (MLP), nontemporal; + one tiny row-update kernel (wave per row).

#define ROW_DIM 128
#define EPSN 1e-12f

typedef float f32x4 __attribute__((ext_vector_type(4)));

// ---------------------------------------------------------------------------
// Bulk copy, 4 independent 16B loads then 4 stores per iteration.
__device__ __forceinline__ void copy_stream(const f32x4* __restrict__ src,
                                            f32x4* __restrict__ dst,
                                            long long n,
                                            long long tid, long long stride)
{
    const long long stride4 = stride * 4;
    long long i = tid;
    for (; i + 3 * stride < n; i += stride4) {
        f32x4 a = __builtin_nontemporal_load(&src[i]);
        f32x4 b = __builtin_nontemporal_load(&src[i + stride]);
        f32x4 c = __builtin_nontemporal_load(&src[i + 2 * stride]);
        f32x4 d = __builtin_nontemporal_load(&src[i + 3 * stride]);
        __builtin_nontemporal_store(a, &dst[i]);
        __builtin_nontemporal_store(b, &dst[i + stride]);
        __builtin_nontemporal_store(c, &dst[i + 2 * stride]);
        __builtin_nontemporal_store(d, &dst[i + 3 * stride]);
    }
    for (; i < n; i += stride) {
        f32x4 a = __builtin_nontemporal_load(&src[i]);
        __builtin_nontemporal_store(a, &dst[i]);
    }
}

__global__ __launch_bounds__(256) void fv_copy_banks(
    const f32x4* __restrict__ src1,
    const f32x4* __restrict__ src2,
    f32x4* __restrict__ dst1,
    f32x4* __restrict__ dst2,
    long long n1v, long long n2v)
{
    const long long tid    = (long long)blockIdx.x * blockDim.x + threadIdx.x;
    const long long stride = (long long)gridDim.x * blockDim.x;
    copy_stream(src1, dst1, n1v, tid, stride);
    copy_stream(src2, dst2, n2v, tid, stride);
}

// ---------------------------------------------------------------------------
// Row update: one 64-lane wave per batch row; each lane owns 2 floats.
__global__ __launch_bounds__(256) void fv_update_rows(
    const float* __restrict__ audio,
    const float* __restrict__ video,
    const float* __restrict__ mem1,
    const float* __restrict__ mem2,
    const int*   __restrict__ y,
    float* __restrict__ out1,
    float* __restrict__ out2,
    int bs)
{
    const int wave = (int)((blockIdx.x * blockDim.x + threadIdx.x) >> 6);
    const int lane = threadIdx.x & 63;
    if (wave >= bs) return;

    const long long row   = (long long)y[wave];
    const long long ebase = (long long)wave * ROW_DIM + lane * 2;
    const long long mbase = row * ROW_DIM + lane * 2;

    // ---------------- audio -> view1 ----------------
    {
        float2 e = *reinterpret_cast<const float2*>(audio + ebase);
        float ss = e.x * e.x + e.y * e.y;
        #pragma unroll
        for (int off = 32; off >= 1; off >>= 1)
            ss += __shfl_xor(ss, off, 64);
        const float n = fmaxf(sqrtf(ss), EPSN);
        const float ax = e.x / n;
        const float ay = e.y / n;

        float2 m = *reinterpret_cast<const float2*>(mem1 + mbase);
        const float lx = m.x * 0.5f + ax * 0.5f;
        const float ly = m.y * 0.5f + ay * 0.5f;
        float ss1 = lx * lx + ly * ly;
        #pragma unroll
        for (int off = 32; off >= 1; off >>= 1)
            ss1 += __shfl_xor(ss1, off, 64);
        const float n1 = fmaxf(sqrtf(ss1), EPSN);
        float2 o;
        o.x = lx / n1;
        o.y = ly / n1;
        *reinterpret_cast<float2*>(out1 + mbase) = o;
    }

    // ---------------- video -> view2 ----------------
    {
        float2 e = *reinterpret_cast<const float2*>(video + ebase);
        float ss = e.x * e.x + e.y * e.y;
        #pragma unroll
        for (int off = 32; off >= 1; off >>= 1)
            ss += __shfl_xor(ss, off, 64);
        const float n = fmaxf(sqrtf(ss), EPSN);
        const float vx = e.x / n;
        const float vy = e.y / n;

        float2 m = *reinterpret_cast<const float2*>(mem2 + mbase);
        const float lx = m.x * 0.5f + vx * 0.5f;
        const float ly = m.y * 0.5f + vy * 0.5f;
        float ss2 = lx * lx + ly * ly;
        #pragma unroll
        for (int off = 32; off >= 1; off >>= 1)
            ss2 += __shfl_xor(ss2, off, 64);
        const float n2 = fmaxf(sqrtf(ss2), EPSN);
        float2 o;
        o.x = lx / n2;
        o.y = ly / n2;
        *reinterpret_cast<float2*>(out2 + mbase) = o;
    }
}

extern "C" void kernel_launch(void* const* d_in, const int* in_sizes, int n_in,
                              void* d_out, int out_size, void* d_ws, size_t ws_size,
                              hipStream_t stream) {
    const float* audio = (const float*)d_in[0];
    const float* video = (const float*)d_in[1];
    const float* mem1  = (const float*)d_in[2];
    const float* mem2  = (const float*)d_in[3];
    const int*   y     = (const int*)d_in[4];

    const int bs       = in_sizes[4];          // 4096
    const long long n1 = in_sizes[2];          // 500000*128 elements
    const long long n2 = in_sizes[3];

    float* out1 = (float*)d_out;
    float* out2 = (float*)d_out + n1;

    // Streaming copy: 4096 blocks x 256 threads (16 waves/CU), 64 B/lane/iter.
    const long long n1v = n1 >> 2;   // float4 count
    const long long n2v = n2 >> 2;
    fv_copy_banks<<<4096, 256, 0, stream>>>(
        (const f32x4*)mem1, (const f32x4*)mem2,
        (f32x4*)out1, (f32x4*)out2, n1v, n2v);

    // Overwrite the updated rows (one wave per row; 4 waves per block).
    const int waves_per_block = 256 / 64;
    const int blocks = (bs + waves_per_block - 1) / waves_per_block;
    fv_update_rows<<<blocks, 256, 0, stream>>>(audio, video, mem1, mem2, y,
                                               out1, out2, bs);
}

// Round 5
// 177.230 us; speedup vs baseline: 1.2754x; 1.2754x over previous
//
#include <hip/hip_runtime.h>
#include <math.h>

// Problem: FVMemoryBank
//   inputs (f32 unless noted):
//     d_in[0] audio_emb  [bs=4096, dim=128]
//     d_in[1] video_emb  [4096, 128]
//     d_in[2] view1_mem  [mem=500000, 128]
//     d_in[3] view2_mem  [500000, 128]
//     d_in[4] y          [4096] int32
//   output: concat(new_view1, new_view2) flat f32 — 2 x 500000 x 128
//
// new_viewK = viewK_mem, except rows y[i] replaced by
//   l2norm( viewK_mem[y[i]]*0.5 + l2norm(embK[i])*0.5 )
//
// Strategy: flat one-float4-per-thread copy (m13-style: plain cached loads,
// no loop, fully coalesced, monotonic) + tiny row-update kernel (wave/row).

#define ROW_DIM 128
#define EPSN 1e-12f

typedef float f32x4 __attribute__((ext_vector_type(4)));

// ---------------------------------------------------------------------------
// Bulk copy: one float4 per thread, both banks in one flat index space.
__global__ __launch_bounds__(256) void fv_copy_banks(
    const f32x4* __restrict__ src1,
    const f32x4* __restrict__ src2,
    f32x4* __restrict__ dst1,
    f32x4* __restrict__ dst2,
    long long n1v, long long n2v)
{
    const long long i = (long long)blockIdx.x * blockDim.x + threadIdx.x;
    if (i < n1v) {
        dst1[i] = src1[i];
    } else {
        const long long j = i - n1v;
        if (j < n2v) dst2[j] = src2[j];
    }
}

// ---------------------------------------------------------------------------
// Row update: one 64-lane wave per batch row; each lane owns 2 floats.
__global__ __launch_bounds__(256) void fv_update_rows(
    const float* __restrict__ audio,
    const float* __restrict__ video,
    const float* __restrict__ mem1,
    const float* __restrict__ mem2,
    const int*   __restrict__ y,
    float* __restrict__ out1,
    float* __restrict__ out2,
    int bs)
{
    const int wave = (int)((blockIdx.x * blockDim.x + threadIdx.x) >> 6);
    const int lane = threadIdx.x & 63;
    if (wave >= bs) return;

    const long long row   = (long long)y[wave];
    const long long ebase = (long long)wave * ROW_DIM + lane * 2;
    const long long mbase = row * ROW_DIM + lane * 2;

    // ---------------- audio -> view1 ----------------
    {
        float2 e = *reinterpret_cast<const float2*>(audio + ebase);
        float ss = e.x * e.x + e.y * e.y;
        #pragma unroll
        for (int off = 32; off >= 1; off >>= 1)
            ss += __shfl_xor(ss, off, 64);
        const float n = fmaxf(sqrtf(ss), EPSN);
        const float ax = e.x / n;
        const float ay = e.y / n;

        float2 m = *reinterpret_cast<const float2*>(mem1 + mbase);
        const float lx = m.x * 0.5f + ax * 0.5f;
        const float ly = m.y * 0.5f + ay * 0.5f;
        float ss1 = lx * lx + ly * ly;
        #pragma unroll
        for (int off = 32; off >= 1; off >>= 1)
            ss1 += __shfl_xor(ss1, off, 64);
        const float n1 = fmaxf(sqrtf(ss1), EPSN);
        float2 o;
        o.x = lx / n1;
        o.y = ly / n1;
        *reinterpret_cast<float2*>(out1 + mbase) = o;
    }

    // ---------------- video -> view2 ----------------
    {
        float2 e = *reinterpret_cast<const float2*>(video + ebase);
        float ss = e.x * e.x + e.y * e.y;
        #pragma unroll
        for (int off = 32; off >= 1; off >>= 1)
            ss += __shfl_xor(ss, off, 64);
        const float n = fmaxf(sqrtf(ss), EPSN);
        const float vx = e.x / n;
        const float vy = e.y / n;

        float2 m = *reinterpret_cast<const float2*>(mem2 + mbase);
        const float lx = m.x * 0.5f + vx * 0.5f;
        const float ly = m.y * 0.5f + vy * 0.5f;
        float ss2 = lx * lx + ly * ly;
        #pragma unroll
        for (int off = 32; off >= 1; off >>= 1)
            ss2 += __shfl_xor(ss2, off, 64);
        const float n2 = fmaxf(sqrtf(ss2), EPSN);
        float2 o;
        o.x = lx / n2;
        o.y = ly / n2;
        *reinterpret_cast<float2*>(out2 + mbase) = o;
    }
}

extern "C" void kernel_launch(void* const* d_in, const int* in_sizes, int n_in,
                              void* d_out, int out_size, void* d_ws, size_t ws_size,
                              hipStream_t stream) {
    const float* audio = (const float*)d_in[0];
    const float* video = (const float*)d_in[1];
    const float* mem1  = (const float*)d_in[2];
    const float* mem2  = (const float*)d_in[3];
    const int*   y     = (const int*)d_in[4];

    const int bs       = in_sizes[4];          // 4096
    const long long n1 = in_sizes[2];          // 500000*128 elements
    const long long n2 = in_sizes[3];

    float* out1 = (float*)d_out;
    float* out2 = (float*)d_out + n1;

    // Flat copy: one thread per float4 across both banks.
    const long long n1v = n1 >> 2;             // 16,000,000
    const long long n2v = n2 >> 2;             // 16,000,000
    const long long total_v = n1v + n2v;       // 32,000,000
    const int blocks = (int)((total_v + 255) / 256);   // 125,000
    fv_copy_banks<<<blocks, 256, 0, stream>>>(
        (const f32x4*)mem1, (const f32x4*)mem2,
        (f32x4*)out1, (f32x4*)out2, n1v, n2v);

    // Overwrite the updated rows (one wave per row; 4 waves per block).
    const int waves_per_block = 256 / 64;
    const int ublocks = (bs + waves_per_block - 1) / waves_per_block;
    fv_update_rows<<<ublocks, 256, 0, stream>>>(audio, video, mem1, mem2, y,
                                                out1, out2, bs);
}